// Round 3
// baseline (270.621 us; speedup 1.0000x reference)
//
#include <hip/hip_runtime.h>

// One wave (64 lanes) per batch element. State: 1024 complex amps = 16/lane
// in registers (re[16], im[16]). s = lane*16 + r ; qubit q <-> s-bit (9-q).
// Bits 0..3 (qubits 6..9): in-register pairs. Bits 4..9 (qubits 0..5):
// cross-lane via __shfl_xor. No LDS, no __syncthreads.
//
// R1: __launch_bounds__(256,4) -> 64 VGPR cap -> full spill (937 MB writes).
// R2: (256,2) -> 128 VGPR cap -> still pinned, still ~290 MB spill traffic.
// R3: (256,1) -> 256 VGPR budget (zero spill) + wave-uniform values
//     (th/ph/ecoef/expA) forced into SGPRs via readfirstlane to cut the
//     longest-lived VGPR ranges by ~27.

__device__ __forceinline__ float wred(float v) {
  v += __shfl_xor(v, 1);
  v += __shfl_xor(v, 2);
  v += __shfl_xor(v, 4);
  v += __shfl_xor(v, 8);
  v += __shfl_xor(v, 16);
  v += __shfl_xor(v, 32);
  return v;
}

// force a wave-uniform float into an SGPR
__device__ __forceinline__ float rfl(float x) {
  return __int_as_float(__builtin_amdgcn_readfirstlane(__float_as_int(x)));
}

template<int BIT>
__device__ __forceinline__ void gate_apply(float (&re)[16], float (&im)[16], int lane,
    float m00r, float m00i, float m01r, float m01i,
    float m10r, float m10i, float m11r, float m11i) {
  if constexpr (BIT < 4) {
    #pragma unroll
    for (int r0 = 0; r0 < 16; ++r0) {
      if ((r0 & (1 << BIT)) == 0) {
        const int r1 = r0 | (1 << BIT);
        const float a0r = re[r0], a0i = im[r0], a1r = re[r1], a1i = im[r1];
        re[r0] = m00r*a0r - m00i*a0i + m01r*a1r - m01i*a1i;
        im[r0] = m00r*a0i + m00i*a0r + m01r*a1i + m01i*a1r;
        re[r1] = m10r*a0r - m10i*a0i + m11r*a1r - m11i*a1i;
        im[r1] = m10r*a0i + m10i*a0r + m11r*a1i + m11i*a1r;
      }
    }
  } else {
    const int lm = 1 << (BIT - 4);
    const bool hi = (lane & lm) != 0;
    // own-amp coeff / partner-amp coeff selected once per gate
    const float cAr = hi ? m11r : m00r, cAi = hi ? m11i : m00i;
    const float cBr = hi ? m10r : m01r, cBi = hi ? m10i : m01i;
    #pragma unroll
    for (int r = 0; r < 16; ++r) {
      const float pr = __shfl_xor(re[r], lm);
      const float pi = __shfl_xor(im[r], lm);
      const float ar = re[r], ai = im[r];
      re[r] = cAr*ar - cAi*ai + cBr*pr - cBi*pi;
      im[r] = cAr*ai + cAi*ar + cBr*pi + cBi*pr;
    }
  }
}

// new[s] = old[ s ^ (ctrlbit(s) ? tgtmask : 0) ]
template<int CB, int TB>
__device__ __forceinline__ void cnot_apply(float (&re)[16], float (&im)[16], int lane) {
  if constexpr (CB >= 4 && TB >= 4) {
    const bool c1 = (lane & (1 << (CB - 4))) != 0;
    #pragma unroll
    for (int r = 0; r < 16; ++r) {
      const float pr = __shfl_xor(re[r], 1 << (TB - 4));
      const float pi = __shfl_xor(im[r], 1 << (TB - 4));
      re[r] = c1 ? pr : re[r];
      im[r] = c1 ? pi : im[r];
    }
  } else if constexpr (CB >= 4 && TB < 4) {
    const bool c1 = (lane & (1 << (CB - 4))) != 0;
    #pragma unroll
    for (int r0 = 0; r0 < 16; ++r0) {
      if ((r0 & (1 << TB)) == 0) {
        const int r1 = r0 | (1 << TB);
        const float ar = re[r0], br = re[r1];
        re[r0] = c1 ? br : ar;  re[r1] = c1 ? ar : br;
        const float ai = im[r0], bi = im[r1];
        im[r0] = c1 ? bi : ai;  im[r1] = c1 ? ai : bi;
      }
    }
  } else if constexpr (CB < 4 && TB >= 4) {
    #pragma unroll
    for (int r = 0; r < 16; ++r) {
      if ((r & (1 << CB)) != 0) {     // compile-time per unrolled r
        re[r] = __shfl_xor(re[r], 1 << (TB - 4));
        im[r] = __shfl_xor(im[r], 1 << (TB - 4));
      }
    }
  } else {
    #pragma unroll
    for (int r0 = 0; r0 < 16; ++r0) {
      if ((r0 & (1 << CB)) != 0 && (r0 & (1 << TB)) == 0) {
        const int r1 = r0 | (1 << TB);
        float t = re[r0]; re[r0] = re[r1]; re[r1] = t;
        t = im[r0]; im[r0] = im[r1]; im[r1] = t;
      }
    }
  }
}

// half_ang(s) = 0.5*pi * sum_p J_p * mask_p(s),  mask = +1 iff bits differ = -z_i z_j
// decomposed: C(lane) [high-high] + d[j]*z_j(r) [high-low] + e[ij]*z_i(r)z_j(r) [low-low]
template<int I, int J>
__device__ __forceinline__ void pair_accum(float t, int lane, float& Cc,
                                           float (&dcf)[4], float (&ecf)[6]) {
  if constexpr (J <= 5) {
    const bool diff = (((lane >> (5 - I)) ^ (lane >> (5 - J))) & 1) != 0;
    Cc += diff ? -t : t;            // t * z_i(lane) * z_j(lane)
  } else if constexpr (I <= 5) {
    const bool b = ((lane >> (5 - I)) & 1) != 0;
    dcf[J - 6] += b ? -t : t;       // t * z_i(lane)
  } else {
    constexpr int eb = (I == 6) ? 0 : (I == 7) ? 3 : 5;
    ecf[eb + (J - I - 1)] = rfl(t); // wave-uniform -> SGPR
  }
}

#define PAIR(i, j) { \
  float dot_ = y0[i]*y0[j] + y1[i]*y1[j]; \
  dot_ = wred(dot_) * (1.0f/127.0f); \
  const float t_ = -1.5707963267948966f * tanhf(dot_ * expA); \
  pair_accum<i, j>(t_, lane, Cc, dcoef, ecoef); }

// full-strength encoding gate: M = RZ(phi) * RY(theta)
#define ENC_FULL(q) { \
  float cy, sy; __sincosf(0.5f * th[q], &sy, &cy); \
  float cz, sz; __sincosf(0.5f * ph[q], &sz, &cz); \
  gate_apply<9 - (q)>(re, im, lane, \
      cy*cz, -cy*sz,  -sy*cz,  sy*sz, \
      sy*cz,  sy*sz,   cy*cz,  cy*sz); }

// layer-0 Rot: M = RZ(w2) RY(w1) RZ(w0)
#define ROT0(q) { \
  const float w0 = vw[(q)*3+0], w1 = vw[(q)*3+1], w2 = vw[(q)*3+2]; \
  float cy, sy; __sincosf(0.5f*w1, &sy, &cy); \
  float ca, sa; __sincosf(0.5f*(w0+w2), &sa, &ca); \
  float cb, sb; __sincosf(0.5f*(w0-w2), &sb, &cb); \
  gate_apply<9 - (q)>(re, im, lane, \
      cy*ca, -cy*sa,  -sy*cb, -sy*sb, \
      sy*cb, -sy*sb,   cy*ca,  cy*sa); }

// fused: EncHalf (RZ(phi/2)RY(theta/2)) followed by layer-l Rot  ->  M = R * E
#define MERGED(l, q) { \
  float cy, sy; __sincosf(0.25f * th[q], &sy, &cy); \
  float cz, sz; __sincosf(0.25f * ph[q], &sz, &cz); \
  const float e00r =  cy*cz, e00i = -cy*sz, e01r = -sy*cz, e01i =  sy*sz; \
  const float e10r =  sy*cz, e10i =  sy*sz, e11r =  cy*cz, e11i =  cy*sz; \
  const float w0 = vw[((l)*10+(q))*3+0], w1 = vw[((l)*10+(q))*3+1], w2 = vw[((l)*10+(q))*3+2]; \
  float cY, sY; __sincosf(0.5f*w1, &sY, &cY); \
  float ca, sa; __sincosf(0.5f*(w0+w2), &sa, &ca); \
  float cb, sb; __sincosf(0.5f*(w0-w2), &sb, &cb); \
  const float r00r =  cY*ca, r00i = -cY*sa, r01r = -sY*cb, r01i = -sY*sb; \
  const float r10r =  sY*cb, r10i = -sY*sb, r11r =  cY*ca, r11i =  cY*sa; \
  const float m00r = r00r*e00r - r00i*e00i + r01r*e10r - r01i*e10i; \
  const float m00i = r00r*e00i + r00i*e00r + r01r*e10i + r01i*e10r; \
  const float m01r = r00r*e01r - r00i*e01i + r01r*e11r - r01i*e11i; \
  const float m01i = r00r*e01i + r00i*e01r + r01r*e11i + r01i*e11r; \
  const float m10r = r10r*e00r - r10i*e00i + r11r*e10r - r11i*e10i; \
  const float m10i = r10r*e00i + r10i*e00r + r11r*e10i + r11i*e10r; \
  const float m11r = r10r*e01r - r10i*e01i + r11r*e11r - r11i*e11i; \
  const float m11i = r10r*e01i + r10i*e01r + r11r*e11i + r11i*e11r; \
  gate_apply<9 - (q)>(re, im, lane, m00r, m00i, m01r, m01i, m10r, m10i, m11r, m11i); }

#define CNOT(ctrl, rng) cnot_apply<9 - (ctrl), 9 - ((((ctrl) + (rng)) % 10))>(re, im, lane);

extern "C" __global__ void __launch_bounds__(256, 1)
qhl_kernel(const float* __restrict__ c_kt, const float* __restrict__ dc_kt,
           const float* __restrict__ vw,  const float* __restrict__ w_proj,
           const float* __restrict__ b_proj, const float* __restrict__ log_alpha,
           float* __restrict__ out) {
  const int wave = threadIdx.x >> 6;
  const int lane = threadIdx.x & 63;
  const int bid  = blockIdx.x * 4 + wave;

  const float* c   = c_kt  + (size_t)bid * 1280;
  const float* dcp = dc_kt + (size_t)bid * 1280;

  // ---- correlation: rows held in registers, stats via wave reductions ----
  float y0[10], y1[10];
  #pragma unroll
  for (int k = 0; k < 10; ++k) {
    y0[k] = c[lane * 10 + k]        + 0.5f * dcp[lane * 10 + k];
    y1[k] = c[(lane + 64) * 10 + k] + 0.5f * dcp[(lane + 64) * 10 + k];
  }
  #pragma unroll
  for (int k = 0; k < 10; ++k) {
    const float mean = wred(y0[k] + y1[k]) * (1.0f / 128.0f);
    y0[k] -= mean; y1[k] -= mean;
    const float ss = wred(y0[k]*y0[k] + y1[k]*y1[k]);
    // rs = 1 / max(sqrt(ss/127), 1e-8)
    const float rs = fminf(__builtin_amdgcn_rsqf(ss * (1.0f / 127.0f)), 1e8f);
    y0[k] *= rs; y1[k] *= rs;
  }

  const float expA = rfl(expf(log_alpha[0]));
  float Cc = 0.0f, dcoef[4] = {0, 0, 0, 0}, ecoef[6];
  PAIR(0,1) PAIR(0,2) PAIR(0,3) PAIR(0,4) PAIR(0,5) PAIR(0,6) PAIR(0,7) PAIR(0,8) PAIR(0,9)
  PAIR(1,2) PAIR(1,3) PAIR(1,4) PAIR(1,5) PAIR(1,6) PAIR(1,7) PAIR(1,8) PAIR(1,9)
  PAIR(2,3) PAIR(2,4) PAIR(2,5) PAIR(2,6) PAIR(2,7) PAIR(2,8) PAIR(2,9)
  PAIR(3,4) PAIR(3,5) PAIR(3,6) PAIR(3,7) PAIR(3,8) PAIR(3,9)
  PAIR(4,5) PAIR(4,6) PAIR(4,7) PAIR(4,8) PAIR(4,9)
  PAIR(5,6) PAIR(5,7) PAIR(5,8) PAIR(5,9)
  PAIR(6,7) PAIR(6,8) PAIR(6,9)
  PAIR(7,8) PAIR(7,9)
  PAIR(8,9)

  // ---- encoding angles: wave-uniform -> force into SGPRs ----
  float th[10], ph[10];
  #pragma unroll
  for (int q = 0; q < 10; ++q) {
    th[q] = rfl(c[1270 + q]);
    ph[q] = rfl(dcp[1270 + q]);
  }

  // ---- state init |0...0> ----
  float re[16], im[16];
  #pragma unroll
  for (int r = 0; r < 16; ++r) { re[r] = 0.0f; im[r] = 0.0f; }
  re[0] = (lane == 0) ? 1.0f : 0.0f;

  // ---- encoding: fused RZ(phi)*RY(theta) per qubit ----
  ENC_FULL(0) ENC_FULL(1) ENC_FULL(2) ENC_FULL(3) ENC_FULL(4)
  ENC_FULL(5) ENC_FULL(6) ENC_FULL(7) ENC_FULL(8) ENC_FULL(9)

  // ---- diagonal ZZ phase ----
  #pragma unroll
  for (int r = 0; r < 16; ++r) {
    const int b3 = (r >> 3) & 1, b2 = (r >> 2) & 1, b1 = (r >> 1) & 1, b0 = r & 1;
    float h = Cc;
    h += b3 ? -dcoef[0] : dcoef[0];
    h += b2 ? -dcoef[1] : dcoef[1];
    h += b1 ? -dcoef[2] : dcoef[2];
    h += b0 ? -dcoef[3] : dcoef[3];
    h += (b3 ^ b2) ? -ecoef[0] : ecoef[0];
    h += (b3 ^ b1) ? -ecoef[1] : ecoef[1];
    h += (b3 ^ b0) ? -ecoef[2] : ecoef[2];
    h += (b2 ^ b1) ? -ecoef[3] : ecoef[3];
    h += (b2 ^ b0) ? -ecoef[4] : ecoef[4];
    h += (b1 ^ b0) ? -ecoef[5] : ecoef[5];
    float sn, cs; __sincosf(h, &sn, &cs);
    const float ar = re[r], ai = im[r];
    re[r] = ar * cs - ai * sn;
    im[r] = ar * sn + ai * cs;
  }

  // ---- layer 0 ----
  ROT0(0) ROT0(1) ROT0(2) ROT0(3) ROT0(4) ROT0(5) ROT0(6) ROT0(7) ROT0(8) ROT0(9)
  CNOT(0,1) CNOT(1,1) CNOT(2,1) CNOT(3,1) CNOT(4,1)
  CNOT(5,1) CNOT(6,1) CNOT(7,1) CNOT(8,1) CNOT(9,1)
  // ---- re-encode(0.5) fused with layer-1 Rot ----
  MERGED(1,0) MERGED(1,1) MERGED(1,2) MERGED(1,3) MERGED(1,4)
  MERGED(1,5) MERGED(1,6) MERGED(1,7) MERGED(1,8) MERGED(1,9)
  CNOT(0,2) CNOT(1,2) CNOT(2,2) CNOT(3,2) CNOT(4,2)
  CNOT(5,2) CNOT(6,2) CNOT(7,2) CNOT(8,2) CNOT(9,2)
  // ---- re-encode(0.5) fused with layer-2 Rot ----
  MERGED(2,0) MERGED(2,1) MERGED(2,2) MERGED(2,3) MERGED(2,4)
  MERGED(2,5) MERGED(2,6) MERGED(2,7) MERGED(2,8) MERGED(2,9)
  CNOT(0,3) CNOT(1,3) CNOT(2,3) CNOT(3,3) CNOT(4,3)
  CNOT(5,3) CNOT(6,3) CNOT(7,3) CNOT(8,3) CNOT(9,3)

  // ---- measurement: Z expvals then 3-action projection ----
  float P = 0.0f, e6 = 0.0f, e7 = 0.0f, e8 = 0.0f, e9 = 0.0f;
  #pragma unroll
  for (int r = 0; r < 16; ++r) {
    const float pp = re[r]*re[r] + im[r]*im[r];
    P  += pp;
    e6 += (r & 8) ? -pp : pp;
    e7 += (r & 4) ? -pp : pp;
    e8 += (r & 2) ? -pp : pp;
    e9 += (r & 1) ? -pp : pp;
  }
  float ev[10];
  ev[0] = (lane & 32) ? -P : P;
  ev[1] = (lane & 16) ? -P : P;
  ev[2] = (lane &  8) ? -P : P;
  ev[3] = (lane &  4) ? -P : P;
  ev[4] = (lane &  2) ? -P : P;
  ev[5] = (lane &  1) ? -P : P;
  ev[6] = e6; ev[7] = e7; ev[8] = e8; ev[9] = e9;
  #pragma unroll
  for (int i = 0; i < 10; ++i) ev[i] = wred(ev[i]);

  if (lane < 3) {
    float acc = b_proj[lane];
    #pragma unroll
    for (int i = 0; i < 10; ++i) acc += w_proj[lane * 10 + i] * ev[i];
    out[(size_t)bid * 3 + lane] = acc;
  }
}

extern "C" void kernel_launch(void* const* d_in, const int* in_sizes, int n_in,
                              void* d_out, int out_size, void* d_ws, size_t ws_size,
                              hipStream_t stream) {
  (void)in_sizes; (void)n_in; (void)d_ws; (void)ws_size; (void)out_size;
  const float* c_kt      = (const float*)d_in[0];
  const float* dc_kt     = (const float*)d_in[1];
  const float* vw        = (const float*)d_in[2];
  const float* w_proj    = (const float*)d_in[3];
  const float* b_proj    = (const float*)d_in[4];
  const float* log_alpha = (const float*)d_in[5];
  float* out = (float*)d_out;
  // 4096 batch elems, 1 wave each, 4 waves per 256-thread block
  qhl_kernel<<<dim3(1024), dim3(256), 0, stream>>>(c_kt, dc_kt, vw, w_proj,
                                                   b_proj, log_alpha, out);
}

// Round 4
// 231.297 us; speedup vs baseline: 1.1700x; 1.1700x over previous
//
#include <hip/hip_runtime.h>

// One wave (64 lanes) per batch element. State: 1024 complex amps = 16/lane
// in registers (re[16], im[16]). s = lane*16 + r ; qubit q <-> s-bit (9-q).
// Bits 0..3 (qubits 6..9): in-register pairs. Bits 4..9 (qubits 0..5):
// cross-lane via __shfl_xor. No LDS, no __syncthreads.
//
// R1: (256,4) -> 64 VGPR cap -> full spill (937 MB writes), 462us.
// R2: (256,2) -> 128 cap, still spills (~290MB, th/ph in VGPRs), 180us.
// R3: (256,1) -> 196 VGPR no-spill BUT 1 wave/SIMD -> latency-bound, 208us.
// R4: (256,2) again, now that th/ph/ecoef live in SGPRs the body fits 128
//     without spilling; + fast tanh (libm tanhf is branchy/reg-hungry) and
//     float2 correlation loads. Want: no-spill AND 4 waves/SIMD.

__device__ __forceinline__ float wred(float v) {
  v += __shfl_xor(v, 1);
  v += __shfl_xor(v, 2);
  v += __shfl_xor(v, 4);
  v += __shfl_xor(v, 8);
  v += __shfl_xor(v, 16);
  v += __shfl_xor(v, 32);
  return v;
}

// force a wave-uniform float into an SGPR
__device__ __forceinline__ float rfl(float x) {
  return __int_as_float(__builtin_amdgcn_readfirstlane(__float_as_int(x)));
}

// tanh(x) = 1 - 2/(exp(2x)+1); __expf saturates correctly at +-inf
__device__ __forceinline__ float fast_tanh(float x) {
  return 1.0f - 2.0f / (__expf(2.0f * x) + 1.0f);
}

template<int BIT>
__device__ __forceinline__ void gate_apply(float (&re)[16], float (&im)[16], int lane,
    float m00r, float m00i, float m01r, float m01i,
    float m10r, float m10i, float m11r, float m11i) {
  if constexpr (BIT < 4) {
    #pragma unroll
    for (int r0 = 0; r0 < 16; ++r0) {
      if ((r0 & (1 << BIT)) == 0) {
        const int r1 = r0 | (1 << BIT);
        const float a0r = re[r0], a0i = im[r0], a1r = re[r1], a1i = im[r1];
        re[r0] = m00r*a0r - m00i*a0i + m01r*a1r - m01i*a1i;
        im[r0] = m00r*a0i + m00i*a0r + m01r*a1i + m01i*a1r;
        re[r1] = m10r*a0r - m10i*a0i + m11r*a1r - m11i*a1i;
        im[r1] = m10r*a0i + m10i*a0r + m11r*a1i + m11i*a1r;
      }
    }
  } else {
    const int lm = 1 << (BIT - 4);
    const bool hi = (lane & lm) != 0;
    // own-amp coeff / partner-amp coeff selected once per gate
    const float cAr = hi ? m11r : m00r, cAi = hi ? m11i : m00i;
    const float cBr = hi ? m10r : m01r, cBi = hi ? m10i : m01i;
    #pragma unroll
    for (int r = 0; r < 16; ++r) {
      const float pr = __shfl_xor(re[r], lm);
      const float pi = __shfl_xor(im[r], lm);
      const float ar = re[r], ai = im[r];
      re[r] = cAr*ar - cAi*ai + cBr*pr - cBi*pi;
      im[r] = cAr*ai + cAi*ar + cBr*pi + cBi*pr;
    }
  }
}

// new[s] = old[ s ^ (ctrlbit(s) ? tgtmask : 0) ]
template<int CB, int TB>
__device__ __forceinline__ void cnot_apply(float (&re)[16], float (&im)[16], int lane) {
  if constexpr (CB >= 4 && TB >= 4) {
    const bool c1 = (lane & (1 << (CB - 4))) != 0;
    #pragma unroll
    for (int r = 0; r < 16; ++r) {
      const float pr = __shfl_xor(re[r], 1 << (TB - 4));
      const float pi = __shfl_xor(im[r], 1 << (TB - 4));
      re[r] = c1 ? pr : re[r];
      im[r] = c1 ? pi : im[r];
    }
  } else if constexpr (CB >= 4 && TB < 4) {
    const bool c1 = (lane & (1 << (CB - 4))) != 0;
    #pragma unroll
    for (int r0 = 0; r0 < 16; ++r0) {
      if ((r0 & (1 << TB)) == 0) {
        const int r1 = r0 | (1 << TB);
        const float ar = re[r0], br = re[r1];
        re[r0] = c1 ? br : ar;  re[r1] = c1 ? ar : br;
        const float ai = im[r0], bi = im[r1];
        im[r0] = c1 ? bi : ai;  im[r1] = c1 ? ai : bi;
      }
    }
  } else if constexpr (CB < 4 && TB >= 4) {
    #pragma unroll
    for (int r = 0; r < 16; ++r) {
      if ((r & (1 << CB)) != 0) {     // compile-time per unrolled r
        re[r] = __shfl_xor(re[r], 1 << (TB - 4));
        im[r] = __shfl_xor(im[r], 1 << (TB - 4));
      }
    }
  } else {
    #pragma unroll
    for (int r0 = 0; r0 < 16; ++r0) {
      if ((r0 & (1 << CB)) != 0 && (r0 & (1 << TB)) == 0) {
        const int r1 = r0 | (1 << TB);
        float t = re[r0]; re[r0] = re[r1]; re[r1] = t;
        t = im[r0]; im[r0] = im[r1]; im[r1] = t;
      }
    }
  }
}

// half_ang(s) = 0.5*pi * sum_p J_p * mask_p(s),  mask = +1 iff bits differ = -z_i z_j
// decomposed: C(lane) [high-high] + d[j]*z_j(r) [high-low] + e[ij]*z_i(r)z_j(r) [low-low]
template<int I, int J>
__device__ __forceinline__ void pair_accum(float t, int lane, float& Cc,
                                           float (&dcf)[4], float (&ecf)[6]) {
  if constexpr (J <= 5) {
    const bool diff = (((lane >> (5 - I)) ^ (lane >> (5 - J))) & 1) != 0;
    Cc += diff ? -t : t;            // t * z_i(lane) * z_j(lane)
  } else if constexpr (I <= 5) {
    const bool b = ((lane >> (5 - I)) & 1) != 0;
    dcf[J - 6] += b ? -t : t;       // t * z_i(lane)
  } else {
    constexpr int eb = (I == 6) ? 0 : (I == 7) ? 3 : 5;
    ecf[eb + (J - I - 1)] = rfl(t); // wave-uniform -> SGPR
  }
}

#define PAIR(i, j) { \
  float dot_ = y0[i]*y0[j] + y1[i]*y1[j]; \
  dot_ = wred(dot_) * (1.0f/127.0f); \
  const float t_ = -1.5707963267948966f * fast_tanh(dot_ * expA); \
  pair_accum<i, j>(t_, lane, Cc, dcoef, ecoef); }

// full-strength encoding gate: M = RZ(phi) * RY(theta)
#define ENC_FULL(q) { \
  float cy, sy; __sincosf(0.5f * th[q], &sy, &cy); \
  float cz, sz; __sincosf(0.5f * ph[q], &sz, &cz); \
  gate_apply<9 - (q)>(re, im, lane, \
      cy*cz, -cy*sz,  -sy*cz,  sy*sz, \
      sy*cz,  sy*sz,   cy*cz,  cy*sz); }

// layer-0 Rot: M = RZ(w2) RY(w1) RZ(w0)
#define ROT0(q) { \
  const float w0 = vw[(q)*3+0], w1 = vw[(q)*3+1], w2 = vw[(q)*3+2]; \
  float cy, sy; __sincosf(0.5f*w1, &sy, &cy); \
  float ca, sa; __sincosf(0.5f*(w0+w2), &sa, &ca); \
  float cb, sb; __sincosf(0.5f*(w0-w2), &sb, &cb); \
  gate_apply<9 - (q)>(re, im, lane, \
      cy*ca, -cy*sa,  -sy*cb, -sy*sb, \
      sy*cb, -sy*sb,   cy*ca,  cy*sa); }

// fused: EncHalf (RZ(phi/2)RY(theta/2)) followed by layer-l Rot  ->  M = R * E
#define MERGED(l, q) { \
  float cy, sy; __sincosf(0.25f * th[q], &sy, &cy); \
  float cz, sz; __sincosf(0.25f * ph[q], &sz, &cz); \
  const float e00r =  cy*cz, e00i = -cy*sz, e01r = -sy*cz, e01i =  sy*sz; \
  const float e10r =  sy*cz, e10i =  sy*sz, e11r =  cy*cz, e11i =  cy*sz; \
  const float w0 = vw[((l)*10+(q))*3+0], w1 = vw[((l)*10+(q))*3+1], w2 = vw[((l)*10+(q))*3+2]; \
  float cY, sY; __sincosf(0.5f*w1, &sY, &cY); \
  float ca, sa; __sincosf(0.5f*(w0+w2), &sa, &ca); \
  float cb, sb; __sincosf(0.5f*(w0-w2), &sb, &cb); \
  const float r00r =  cY*ca, r00i = -cY*sa, r01r = -sY*cb, r01i = -sY*sb; \
  const float r10r =  sY*cb, r10i = -sY*sb, r11r =  cY*ca, r11i =  cY*sa; \
  const float m00r = r00r*e00r - r00i*e00i + r01r*e10r - r01i*e10i; \
  const float m00i = r00r*e00i + r00i*e00r + r01r*e10i + r01i*e10r; \
  const float m01r = r00r*e01r - r00i*e01i + r01r*e11r - r01i*e11i; \
  const float m01i = r00r*e01i + r00i*e01r + r01r*e11i + r01i*e11r; \
  const float m10r = r10r*e00r - r10i*e00i + r11r*e10r - r11i*e10i; \
  const float m10i = r10r*e00i + r10i*e00r + r11r*e10i + r11i*e10r; \
  const float m11r = r10r*e01r - r10i*e01i + r11r*e11r - r11i*e11i; \
  const float m11i = r10r*e01i + r10i*e01r + r11r*e11i + r11i*e11r; \
  gate_apply<9 - (q)>(re, im, lane, m00r, m00i, m01r, m01i, m10r, m10i, m11r, m11i); }

#define CNOT(ctrl, rng) cnot_apply<9 - (ctrl), 9 - ((((ctrl) + (rng)) % 10))>(re, im, lane);

extern "C" __global__ void __launch_bounds__(256, 2)
qhl_kernel(const float* __restrict__ c_kt, const float* __restrict__ dc_kt,
           const float* __restrict__ vw,  const float* __restrict__ w_proj,
           const float* __restrict__ b_proj, const float* __restrict__ log_alpha,
           float* __restrict__ out) {
  const int wave = threadIdx.x >> 6;
  const int lane = threadIdx.x & 63;
  const int bid  = blockIdx.x * 4 + wave;

  const float* c   = c_kt  + (size_t)bid * 1280;
  const float* dcp = dc_kt + (size_t)bid * 1280;

  // ---- correlation: rows held in registers, stats via wave reductions ----
  // row stride 10 floats = 40B = 8B-aligned -> float2 loads (5 per row)
  float y0[10], y1[10];
  {
    const float2* c0 = (const float2*)(c   + lane * 10);
    const float2* d0 = (const float2*)(dcp + lane * 10);
    const float2* c1 = (const float2*)(c   + (lane + 64) * 10);
    const float2* d1 = (const float2*)(dcp + (lane + 64) * 10);
    #pragma unroll
    for (int k = 0; k < 5; ++k) {
      const float2 a0 = c0[k], b0 = d0[k], a1 = c1[k], b1 = d1[k];
      y0[2*k]   = a0.x + 0.5f * b0.x;  y0[2*k+1] = a0.y + 0.5f * b0.y;
      y1[2*k]   = a1.x + 0.5f * b1.x;  y1[2*k+1] = a1.y + 0.5f * b1.y;
    }
  }
  #pragma unroll
  for (int k = 0; k < 10; ++k) {
    const float mean = wred(y0[k] + y1[k]) * (1.0f / 128.0f);
    y0[k] -= mean; y1[k] -= mean;
    const float ss = wred(y0[k]*y0[k] + y1[k]*y1[k]);
    // rs = 1 / max(sqrt(ss/127), 1e-8)
    const float rs = fminf(__builtin_amdgcn_rsqf(ss * (1.0f / 127.0f)), 1e8f);
    y0[k] *= rs; y1[k] *= rs;
  }

  const float expA = rfl(__expf(log_alpha[0]));
  float Cc = 0.0f, dcoef[4] = {0, 0, 0, 0}, ecoef[6];
  PAIR(0,1) PAIR(0,2) PAIR(0,3) PAIR(0,4) PAIR(0,5) PAIR(0,6) PAIR(0,7) PAIR(0,8) PAIR(0,9)
  PAIR(1,2) PAIR(1,3) PAIR(1,4) PAIR(1,5) PAIR(1,6) PAIR(1,7) PAIR(1,8) PAIR(1,9)
  PAIR(2,3) PAIR(2,4) PAIR(2,5) PAIR(2,6) PAIR(2,7) PAIR(2,8) PAIR(2,9)
  PAIR(3,4) PAIR(3,5) PAIR(3,6) PAIR(3,7) PAIR(3,8) PAIR(3,9)
  PAIR(4,5) PAIR(4,6) PAIR(4,7) PAIR(4,8) PAIR(4,9)
  PAIR(5,6) PAIR(5,7) PAIR(5,8) PAIR(5,9)
  PAIR(6,7) PAIR(6,8) PAIR(6,9)
  PAIR(7,8) PAIR(7,9)
  PAIR(8,9)

  // ---- encoding angles: wave-uniform -> force into SGPRs ----
  float th[10], ph[10];
  #pragma unroll
  for (int q = 0; q < 10; ++q) {
    th[q] = rfl(c[1270 + q]);
    ph[q] = rfl(dcp[1270 + q]);
  }

  // ---- state init |0...0> ----
  float re[16], im[16];
  #pragma unroll
  for (int r = 0; r < 16; ++r) { re[r] = 0.0f; im[r] = 0.0f; }
  re[0] = (lane == 0) ? 1.0f : 0.0f;

  // ---- encoding: fused RZ(phi)*RY(theta) per qubit ----
  ENC_FULL(0) ENC_FULL(1) ENC_FULL(2) ENC_FULL(3) ENC_FULL(4)
  ENC_FULL(5) ENC_FULL(6) ENC_FULL(7) ENC_FULL(8) ENC_FULL(9)

  // ---- diagonal ZZ phase ----
  #pragma unroll
  for (int r = 0; r < 16; ++r) {
    const int b3 = (r >> 3) & 1, b2 = (r >> 2) & 1, b1 = (r >> 1) & 1, b0 = r & 1;
    float h = Cc;
    h += b3 ? -dcoef[0] : dcoef[0];
    h += b2 ? -dcoef[1] : dcoef[1];
    h += b1 ? -dcoef[2] : dcoef[2];
    h += b0 ? -dcoef[3] : dcoef[3];
    h += (b3 ^ b2) ? -ecoef[0] : ecoef[0];
    h += (b3 ^ b1) ? -ecoef[1] : ecoef[1];
    h += (b3 ^ b0) ? -ecoef[2] : ecoef[2];
    h += (b2 ^ b1) ? -ecoef[3] : ecoef[3];
    h += (b2 ^ b0) ? -ecoef[4] : ecoef[4];
    h += (b1 ^ b0) ? -ecoef[5] : ecoef[5];
    float sn, cs; __sincosf(h, &sn, &cs);
    const float ar = re[r], ai = im[r];
    re[r] = ar * cs - ai * sn;
    im[r] = ar * sn + ai * cs;
  }

  // ---- layer 0 ----
  ROT0(0) ROT0(1) ROT0(2) ROT0(3) ROT0(4) ROT0(5) ROT0(6) ROT0(7) ROT0(8) ROT0(9)
  CNOT(0,1) CNOT(1,1) CNOT(2,1) CNOT(3,1) CNOT(4,1)
  CNOT(5,1) CNOT(6,1) CNOT(7,1) CNOT(8,1) CNOT(9,1)
  // ---- re-encode(0.5) fused with layer-1 Rot ----
  MERGED(1,0) MERGED(1,1) MERGED(1,2) MERGED(1,3) MERGED(1,4)
  MERGED(1,5) MERGED(1,6) MERGED(1,7) MERGED(1,8) MERGED(1,9)
  CNOT(0,2) CNOT(1,2) CNOT(2,2) CNOT(3,2) CNOT(4,2)
  CNOT(5,2) CNOT(6,2) CNOT(7,2) CNOT(8,2) CNOT(9,2)
  // ---- re-encode(0.5) fused with layer-2 Rot ----
  MERGED(2,0) MERGED(2,1) MERGED(2,2) MERGED(2,3) MERGED(2,4)
  MERGED(2,5) MERGED(2,6) MERGED(2,7) MERGED(2,8) MERGED(2,9)
  CNOT(0,3) CNOT(1,3) CNOT(2,3) CNOT(3,3) CNOT(4,3)
  CNOT(5,3) CNOT(6,3) CNOT(7,3) CNOT(8,3) CNOT(9,3)

  // ---- measurement: Z expvals then 3-action projection ----
  float P = 0.0f, e6 = 0.0f, e7 = 0.0f, e8 = 0.0f, e9 = 0.0f;
  #pragma unroll
  for (int r = 0; r < 16; ++r) {
    const float pp = re[r]*re[r] + im[r]*im[r];
    P  += pp;
    e6 += (r & 8) ? -pp : pp;
    e7 += (r & 4) ? -pp : pp;
    e8 += (r & 2) ? -pp : pp;
    e9 += (r & 1) ? -pp : pp;
  }
  float ev[10];
  ev[0] = (lane & 32) ? -P : P;
  ev[1] = (lane & 16) ? -P : P;
  ev[2] = (lane &  8) ? -P : P;
  ev[3] = (lane &  4) ? -P : P;
  ev[4] = (lane &  2) ? -P : P;
  ev[5] = (lane &  1) ? -P : P;
  ev[6] = e6; ev[7] = e7; ev[8] = e8; ev[9] = e9;
  #pragma unroll
  for (int i = 0; i < 10; ++i) ev[i] = wred(ev[i]);

  if (lane < 3) {
    float acc = b_proj[lane];
    #pragma unroll
    for (int i = 0; i < 10; ++i) acc += w_proj[lane * 10 + i] * ev[i];
    out[(size_t)bid * 3 + lane] = acc;
  }
}

extern "C" void kernel_launch(void* const* d_in, const int* in_sizes, int n_in,
                              void* d_out, int out_size, void* d_ws, size_t ws_size,
                              hipStream_t stream) {
  (void)in_sizes; (void)n_in; (void)d_ws; (void)ws_size; (void)out_size;
  const float* c_kt      = (const float*)d_in[0];
  const float* dc_kt     = (const float*)d_in[1];
  const float* vw        = (const float*)d_in[2];
  const float* w_proj    = (const float*)d_in[3];
  const float* b_proj    = (const float*)d_in[4];
  const float* log_alpha = (const float*)d_in[5];
  float* out = (float*)d_out;
  // 4096 batch elems, 1 wave each, 4 waves per 256-thread block
  qhl_kernel<<<dim3(1024), dim3(256), 0, stream>>>(c_kt, dc_kt, vw, w_proj,
                                                   b_proj, log_alpha, out);
}